// Round 1
// baseline (229.005 us; speedup 1.0000x reference)
//
#include <hip/hip_runtime.h>

#define B_DIM 8
#define N_DIM 2048
#define F_DIM 128

typedef __attribute__((ext_vector_type(8))) __bf16 bf16x8;
typedef __attribute__((ext_vector_type(4))) float f32x4;

__device__ __forceinline__ __bf16 f2bf(float f) {
  unsigned u = __builtin_bit_cast(unsigned, f);
  u += 0x7FFFu + ((u >> 16) & 1u);                 // round-to-nearest-even
  unsigned short s = (unsigned short)(u >> 16);
  return __builtin_bit_cast(__bf16, s);
}

// Kernel 1: supT[b][j][i] = bf16( sum_f x[b][i][f] * W[f][j] )   (transposed!)
// LDS-free version: each wave gathers its W^T A-fragments (32 j x 128 f)
// straight from global into 32 VGPRs (W is 64 KB, L2-resident after first
// touch), no barrier. Grid 512 = 2 blocks/CU, 8 waves/CU for latency hiding.
__global__ __launch_bounds__(256) void gcn_xw(const float* __restrict__ x,
                                              const float* __restrict__ W,
                                              __bf16* __restrict__ supT) {
  const int tid = threadIdx.x;
  const int lane = tid & 63;
  const int wave = tid >> 6;
  const int b = blockIdx.x >> 6;
  const int i0 = (blockIdx.x & 63) << 5;   // 32 nodes per WG

  const int jt0 = wave << 1;           // each wave: 2 j-tiles x 2 i-tiles
  const int q8 = (lane >> 4) << 3;     // k offset of this quad
  const int c = lane & 15;

  // A fragments: af[jt][k4] = W^T[j = tile*16+c][f = k4*32+q8 .. +8].
  // Per instruction lanes 0..15 read consecutive j -> 64B segments, L2 hits.
  bf16x8 af[2][4];
#pragma unroll
  for (int jt = 0; jt < 2; ++jt) {
    const int j = (jt0 + jt) * 16 + c;
#pragma unroll
    for (int k4 = 0; k4 < 4; ++k4) {
      const int f0 = k4 * 32 + q8;
      bf16x8 v;
#pragma unroll
      for (int e = 0; e < 8; ++e)
        v[e] = f2bf(W[(size_t)(f0 + e) * 128 + j]);
      af[jt][k4] = v;
    }
  }

  f32x4 acc[2][2] = {};
  const float* xb = x + ((size_t)b * N_DIM + i0) * F_DIM;

#pragma unroll
  for (int k4 = 0; k4 < 4; ++k4) {
    const int kq = k4 * 32 + q8;
    bf16x8 bfr[2];
#pragma unroll
    for (int nt = 0; nt < 2; ++nt) {
      const float* xp = xb + (size_t)(nt * 16 + c) * F_DIM + kq;
      f32x4 x0 = *reinterpret_cast<const f32x4*>(xp);
      f32x4 x1 = *reinterpret_cast<const f32x4*>(xp + 4);
      bf16x8 v;
      v[0] = f2bf(x0.x); v[1] = f2bf(x0.y); v[2] = f2bf(x0.z); v[3] = f2bf(x0.w);
      v[4] = f2bf(x1.x); v[5] = f2bf(x1.y); v[6] = f2bf(x1.z); v[7] = f2bf(x1.w);
      bfr[nt] = v;
    }
#pragma unroll
    for (int jt = 0; jt < 2; ++jt)
#pragma unroll
      for (int nt = 0; nt < 2; ++nt)
        acc[jt][nt] = __builtin_amdgcn_mfma_f32_16x16x32_bf16(af[jt][k4], bfr[nt],
                                                              acc[jt][nt], 0, 0, 0);
  }

  __bf16* sb = supT + (size_t)b * F_DIM * N_DIM;
  const int q = lane >> 4;
#pragma unroll
  for (int jt = 0; jt < 2; ++jt)
#pragma unroll
    for (int nt = 0; nt < 2; ++nt)
#pragma unroll
      for (int r = 0; r < 4; ++r) {
        int j = (jt0 + jt) * 16 + q * 4 + r;   // D row = quad*4 + reg
        int i = i0 + nt * 16 + c;              // D col = lane&15
        sb[(size_t)j * N_DIM + i] = f2bf(acc[jt][nt][r]);
      }
}

// Kernel 2: out[b][m][j] = sum_k adj[b][m][k] * supT[b][j][k] + bias[j]
// 32(M) x 128(N) tile per 256-thr WG. b = blockIdx&7 pins each batch to one
// XCD so supT[b] (512 KB) stays in that L2; adj reads nontemporal.
// supT tile staged via global_load_lds width-16 (no VGPR round trip):
// linear LDS [128 n][8 slots of 16B], slot s holds k-oct (s ^ (n&7))
// -- XOR applied on the pre-swizzled GLOBAL source (m173 pattern) and again
// on the ds_read_b128, giving a 2-way (free) bank pattern instead of 16-way.
// adj tile is reg-staged (needs f32->bf16 convert), pad-72 layout.
__global__ __launch_bounds__(256, 2) void gcn_adj(const float* __restrict__ adj,
                                                  const __bf16* __restrict__ supT,
                                                  const float* __restrict__ bias,
                                                  float* __restrict__ out) {
  __shared__ __bf16 As[2][32 * 72];    // adj tile [m][k] bf16, stride 72
  __shared__ __bf16 Bs[2][128 * 64];   // supT tile, oct-swizzled linear
  const int tid = threadIdx.x;
  const int lane = tid & 63;
  const int wave = tid >> 6;
  const int b = blockIdx.x & 7;
  const int m0 = (blockIdx.x >> 3) << 5;

  const int nsub = wave << 5;          // each wave: full 32(M) x 32(N)

  const float* adjb = adj + ((size_t)b * N_DIM + m0) * N_DIM;
  const __bf16* sb = supT + (size_t)b * F_DIM * N_DIM;

  const int arow = tid >> 3;           // adj staging: 8 thr/row, 8 f32 each
  const int acol = (tid & 7) << 3;

  f32x4 pa[2];

  auto issue_adj = [&](int kk) {
    const f32x4* ap = reinterpret_cast<const f32x4*>(adjb + (size_t)arow * N_DIM + kk + acol);
    pa[0] = __builtin_nontemporal_load(ap);
    pa[1] = __builtin_nontemporal_load(ap + 1);
  };
  auto issue_sup = [&](int kk, int buf) {
    // chunk L = i*256+tid -> row n = L>>3, slot L&7; source oct = slot^(n&7)
#pragma unroll
    for (int i = 0; i < 4; ++i) {
      const int L = i * 256 + tid;
      const int n = L >> 3;
      const int s = (L & 7) ^ (n & 7);
      const __bf16* src = sb + (size_t)n * N_DIM + kk + (s << 3);
      // wave-uniform LDS base: elem (i*256 + wave*64)*8; lane adds 16B
      __bf16* dst = &Bs[buf][i * 2048 + ((tid & 192) << 3)];
      __builtin_amdgcn_global_load_lds(
          (const __attribute__((address_space(1))) void*)src,
          (__attribute__((address_space(3))) void*)dst, 16, 0, 0);
    }
  };
  auto store_adj = [&](int buf) {
    bf16x8 v;
    v[0] = f2bf(pa[0].x); v[1] = f2bf(pa[0].y); v[2] = f2bf(pa[0].z); v[3] = f2bf(pa[0].w);
    v[4] = f2bf(pa[1].x); v[5] = f2bf(pa[1].y); v[6] = f2bf(pa[1].z); v[7] = f2bf(pa[1].w);
    *reinterpret_cast<bf16x8*>(&As[buf][arow * 72 + acol]) = v;
  };

  f32x4 acc[2][2] = {};
  const int q = lane >> 4;
  const int q8 = q << 3;
  const int c = lane & 15;
  const int c7 = c & 7;

  issue_sup(0, 0);
  issue_adj(0);
  store_adj(0);
  __syncthreads();   // vmcnt(0)+lgkmcnt(0) drain: gload_lds + ds_write landed

  for (int it = 1; it <= 32; ++it) {
    const int cur = (it - 1) & 1;
    const int nxt = it & 1;
    if (it < 32) {              // next tile's loads in flight over compute
      issue_sup(it * 64, nxt);
      issue_adj(it * 64);
    }
#pragma unroll
    for (int k2 = 0; k2 < 2; ++k2) {
      bf16x8 af[2], bfr[2];
#pragma unroll
      for (int mt = 0; mt < 2; ++mt)
        af[mt] = *reinterpret_cast<const bf16x8*>(&As[cur][(mt * 16 + c) * 72 + k2 * 32 + q8]);
#pragma unroll
      for (int nt = 0; nt < 2; ++nt) {
        const int n = nsub + nt * 16 + c;
        const int s = ((k2 << 2) + q) ^ c7;      // un-swizzle on read
        bfr[nt] = *reinterpret_cast<const bf16x8*>(&Bs[cur][n * 64 + (s << 3)]);
      }
#pragma unroll
      for (int mt = 0; mt < 2; ++mt)
#pragma unroll
        for (int nt = 0; nt < 2; ++nt)
          acc[mt][nt] = __builtin_amdgcn_mfma_f32_16x16x32_bf16(af[mt], bfr[nt],
                                                                acc[mt][nt], 0, 0, 0);
    }
    if (it < 32) store_adj(nxt);
    __syncthreads();
  }

  float bv[2];
#pragma unroll
  for (int nt = 0; nt < 2; ++nt) bv[nt] = bias[nsub + nt * 16 + c];
#pragma unroll
  for (int mt = 0; mt < 2; ++mt)
#pragma unroll
    for (int nt = 0; nt < 2; ++nt)
#pragma unroll
      for (int r = 0; r < 4; ++r) {
        int m = m0 + mt * 16 + q * 4 + r;
        int j = nsub + nt * 16 + c;
        __builtin_nontemporal_store(acc[mt][nt][r] + bv[nt],
                                    &out[((size_t)b * N_DIM + m) * F_DIM + j]);
      }
}

extern "C" void kernel_launch(void* const* d_in, const int* in_sizes, int n_in,
                              void* d_out, int out_size, void* d_ws, size_t ws_size,
                              hipStream_t stream) {
  const float* x    = (const float*)d_in[0];
  const float* adj  = (const float*)d_in[1];
  const float* W    = (const float*)d_in[2];
  const float* bias = (const float*)d_in[3];
  float* out = (float*)d_out;
  __bf16* supT = (__bf16*)d_ws;   // 8*128*2048*2 = 4 MB scratch

  gcn_xw<<<B_DIM * 64, 256, 0, stream>>>(x, W, supT);
  gcn_adj<<<B_DIM * 64, 256, 0, stream>>>(adj, supT, bias, out);
}

// Round 2
// 216.746 us; speedup vs baseline: 1.0566x; 1.0566x over previous
//
#include <hip/hip_runtime.h>

#define B_DIM 8
#define N_DIM 2048
#define F_DIM 128

typedef __attribute__((ext_vector_type(8))) __bf16 bf16x8;
typedef __attribute__((ext_vector_type(4))) float f32x4;

__device__ __forceinline__ __bf16 f2bf(float f) {
  unsigned u = __builtin_bit_cast(unsigned, f);
  u += 0x7FFFu + ((u >> 16) & 1u);                 // round-to-nearest-even
  unsigned short s = (unsigned short)(u >> 16);
  return __builtin_bit_cast(__bf16, s);
}

// Kernel 1: supT[b][j][i] = bf16( sum_f x[b][i][f] * W[f][j] )   (transposed!)
// (reverted to the harness-verified 217us version: LDS-staged W^T, 64-node
// tiles, 256 blocks)
__global__ __launch_bounds__(256) void gcn_xw(const float* __restrict__ x,
                                              const float* __restrict__ W,
                                              __bf16* __restrict__ supT) {
  __shared__ __bf16 WT[128 * 136];   // [j][f], stride 136 -> 2-way banks on read
  const int tid = threadIdx.x;
  const int lane = tid & 63;
  const int wave = tid >> 6;
  const int b = blockIdx.x >> 5;
  const int i0 = (blockIdx.x & 31) << 6;   // 64 nodes per WG

  {
    const int j = tid & 127;
    const int fh = (tid >> 7) << 6;          // 0 or 64
#pragma unroll
    for (int p = 0; p < 8; ++p) {
      const int f0 = fh + p * 8;
      bf16x8 v;
#pragma unroll
      for (int e = 0; e < 8; ++e)
        v[e] = f2bf(W[(size_t)(f0 + e) * 128 + j]);
      *reinterpret_cast<bf16x8*>(&WT[j * 136 + f0]) = v;
    }
  }
  __syncthreads();

  const int jt0 = wave << 1;           // each wave: 2 j-tiles x 4 i-tiles
  const int q8 = (lane >> 4) << 3;     // k offset of this quad
  const int c = lane & 15;
  f32x4 acc[2][4] = {};
  const float* xb = x + ((size_t)b * N_DIM + i0) * F_DIM;

  for (int k0 = 0; k0 < 128; k0 += 32) {
    const int kq = k0 + q8;
    bf16x8 af[2], bfr[4];
#pragma unroll
    for (int jt = 0; jt < 2; ++jt)
      af[jt] = *reinterpret_cast<const bf16x8*>(&WT[((jt0 + jt) * 16 + c) * 136 + kq]);
#pragma unroll
    for (int nt = 0; nt < 4; ++nt) {
      const float* xp = xb + (size_t)(nt * 16 + c) * F_DIM + kq;
      f32x4 x0 = *reinterpret_cast<const f32x4*>(xp);
      f32x4 x1 = *reinterpret_cast<const f32x4*>(xp + 4);
      bf16x8 v;
      v[0] = f2bf(x0.x); v[1] = f2bf(x0.y); v[2] = f2bf(x0.z); v[3] = f2bf(x0.w);
      v[4] = f2bf(x1.x); v[5] = f2bf(x1.y); v[6] = f2bf(x1.z); v[7] = f2bf(x1.w);
      bfr[nt] = v;
    }
#pragma unroll
    for (int jt = 0; jt < 2; ++jt)
#pragma unroll
      for (int nt = 0; nt < 4; ++nt)
        acc[jt][nt] = __builtin_amdgcn_mfma_f32_16x16x32_bf16(af[jt], bfr[nt],
                                                              acc[jt][nt], 0, 0, 0);
  }

  __bf16* sb = supT + (size_t)b * F_DIM * N_DIM;
  const int q = lane >> 4;
#pragma unroll
  for (int jt = 0; jt < 2; ++jt)
#pragma unroll
    for (int nt = 0; nt < 4; ++nt)
#pragma unroll
      for (int r = 0; r < 4; ++r) {
        int j = (jt0 + jt) * 16 + q * 4 + r;   // D row = quad*4 + reg
        int i = i0 + nt * 16 + c;              // D col = lane&15
        sb[(size_t)j * N_DIM + i] = f2bf(acc[jt][nt][r]);
      }
}

// Kernel 2: out[b][m][j] = sum_k adj[b][m][k] * supT[b][j][k] + bias[j]
// 32(M) x 128(N) tile per 256-thr WG, grid 512 = 2 blocks/CU. b = blockIdx&7
// pins each batch's supT (512 KB) to one XCD L2; adj reads nontemporal.
//
// T3/T4-lite pipeline: supT staged via global_load_lds width-16 into a
// TRIPLE-buffered linear LDS tile (oct-XOR swizzle applied on the global
// source and again on ds_read -> 2-way/free bank pattern). Prefetch runs
// 2 K-tiles deep; barriers use raw s_barrier + counted vmcnt(4) so the
// next-next tile's loads stay in flight ACROSS the barrier (no vmcnt(0)
// drain per iteration). Queue at the wait: sup(t+1)x4 [oldest] + adj(t+1)x2
// + sup(t+2)x4 = 10 -> vmcnt(4) retires sup(t+1)+adj under ANY issue order.
// Bs[t%3] is only rewritten by loads issued at t+1, after the barrier where
// every wave has drained lgkmcnt(0) (reads retired) -> no race.
__global__ __launch_bounds__(256, 2) void gcn_adj(const float* __restrict__ adj,
                                                  const __bf16* __restrict__ supT,
                                                  const float* __restrict__ bias,
                                                  float* __restrict__ out) {
  __shared__ __bf16 As[2][32 * 72];    // adj tile [m][k] bf16, stride 72
  __shared__ __bf16 Bs[3][128 * 64];   // supT tile, oct-swizzled linear, 3-buf
  const int tid = threadIdx.x;
  const int lane = tid & 63;
  const int wave = tid >> 6;
  const int b = blockIdx.x & 7;
  const int m0 = (blockIdx.x >> 3) << 5;

  const int nsub = wave << 5;          // each wave: full 32(M) x 32(N)

  const float* adjb = adj + ((size_t)b * N_DIM + m0) * N_DIM;
  const __bf16* sb = supT + (size_t)b * F_DIM * N_DIM;

  const int arow = tid >> 3;           // adj staging: 8 thr/row, 8 f32 each
  const int acol = (tid & 7) << 3;

  f32x4 pa[2];

  auto issue_adj = [&](int kk) {
    const f32x4* ap = reinterpret_cast<const f32x4*>(adjb + (size_t)arow * N_DIM + kk + acol);
    pa[0] = __builtin_nontemporal_load(ap);
    pa[1] = __builtin_nontemporal_load(ap + 1);
  };
  auto issue_sup = [&](int kk, int buf) {
    // chunk L = i*256+tid -> row n = L>>3, slot L&7; source oct = slot^(n&7)
#pragma unroll
    for (int i = 0; i < 4; ++i) {
      const int L = i * 256 + tid;
      const int n = L >> 3;
      const int s = (L & 7) ^ (n & 7);
      const __bf16* src = sb + (size_t)n * N_DIM + kk + (s << 3);
      // wave-uniform LDS base: elem (i*256 + wave*64)*8; lane adds 16B
      __bf16* dst = &Bs[buf][i * 2048 + ((tid & 192) << 3)];
      __builtin_amdgcn_global_load_lds(
          (const __attribute__((address_space(1))) void*)src,
          (__attribute__((address_space(3))) void*)dst, 16, 0, 0);
    }
  };
  auto store_adj = [&](int buf) {
    bf16x8 v;
    v[0] = f2bf(pa[0].x); v[1] = f2bf(pa[0].y); v[2] = f2bf(pa[0].z); v[3] = f2bf(pa[0].w);
    v[4] = f2bf(pa[1].x); v[5] = f2bf(pa[1].y); v[6] = f2bf(pa[1].z); v[7] = f2bf(pa[1].w);
    *reinterpret_cast<bf16x8*>(&As[buf][arow * 72 + acol]) = v;
  };

  f32x4 acc[2][2] = {};
  const int q = lane >> 4;
  const int q8 = q << 3;
  const int c = lane & 15;
  const int c7 = c & 7;

  // Prologue: sup(0), adj(0), sup(1) in flight; wait only the first 6.
  issue_sup(0, 0);
  issue_adj(0);
  issue_sup(64, 1);
  asm volatile("s_waitcnt vmcnt(4)" ::: "memory");
  __builtin_amdgcn_sched_barrier(0);
  store_adj(0);
  asm volatile("s_waitcnt lgkmcnt(0)" ::: "memory");
  __builtin_amdgcn_sched_barrier(0);
  __builtin_amdgcn_s_barrier();

  for (int t = 0; t < 32; ++t) {
    const int cur = t % 3;
    const int curA = t & 1;
    // issue next adj (regs) + next-next sup (gload_lds) BEFORE compute
    if (t < 31) issue_adj((t + 1) * 64);
    if (t < 30) issue_sup((t + 2) * 64, (t + 2) % 3);
    __builtin_amdgcn_sched_barrier(0);   // pin issues ahead of the MFMA cluster
#pragma unroll
    for (int k2 = 0; k2 < 2; ++k2) {
      bf16x8 af[2], bfr[2];
#pragma unroll
      for (int mt = 0; mt < 2; ++mt)
        af[mt] = *reinterpret_cast<const bf16x8*>(&As[curA][(mt * 16 + c) * 72 + k2 * 32 + q8]);
#pragma unroll
      for (int nt = 0; nt < 2; ++nt) {
        const int n = nsub + nt * 16 + c;
        const int s = ((k2 << 2) + q) ^ c7;      // un-swizzle on read
        bfr[nt] = *reinterpret_cast<const bf16x8*>(&Bs[cur][n * 64 + (s << 3)]);
      }
#pragma unroll
      for (int mt = 0; mt < 2; ++mt)
#pragma unroll
        for (int nt = 0; nt < 2; ++nt)
          acc[mt][nt] = __builtin_amdgcn_mfma_f32_16x16x32_bf16(af[mt], bfr[nt],
                                                                acc[mt][nt], 0, 0, 0);
    }
    if (t < 31) {
      if (t < 30)
        asm volatile("s_waitcnt vmcnt(4)" ::: "memory");   // sup(t+1)+adj landed
      else
        asm volatile("s_waitcnt vmcnt(0)" ::: "memory");   // tail drain
      __builtin_amdgcn_sched_barrier(0);
      store_adj((t + 1) & 1);
      asm volatile("s_waitcnt lgkmcnt(0)" ::: "memory");   // ds ops retired
      __builtin_amdgcn_sched_barrier(0);
      __builtin_amdgcn_s_barrier();
    }
  }

  float bv[2];
#pragma unroll
  for (int nt = 0; nt < 2; ++nt) bv[nt] = bias[nsub + nt * 16 + c];
#pragma unroll
  for (int mt = 0; mt < 2; ++mt)
#pragma unroll
    for (int nt = 0; nt < 2; ++nt)
#pragma unroll
      for (int r = 0; r < 4; ++r) {
        int m = m0 + mt * 16 + q * 4 + r;
        int j = nsub + nt * 16 + c;
        __builtin_nontemporal_store(acc[mt][nt][r] + bv[nt],
                                    &out[((size_t)b * N_DIM + m) * F_DIM + j]);
      }
}

extern "C" void kernel_launch(void* const* d_in, const int* in_sizes, int n_in,
                              void* d_out, int out_size, void* d_ws, size_t ws_size,
                              hipStream_t stream) {
  const float* x    = (const float*)d_in[0];
  const float* adj  = (const float*)d_in[1];
  const float* W    = (const float*)d_in[2];
  const float* bias = (const float*)d_in[3];
  float* out = (float*)d_out;
  __bf16* supT = (__bf16*)d_ws;   // 8*128*2048*2 = 4 MB scratch

  gcn_xw<<<B_DIM * 32, 256, 0, stream>>>(x, W, supT);
  gcn_adj<<<B_DIM * 64, 256, 0, stream>>>(adj, supT, bias, out);
}